// Round 1
// baseline (191.483 us; speedup 1.0000x reference)
//
#include <hip/hip_runtime.h>
#include <hip/hip_bf16.h>

// IndexedLinear: out[n] = x[n] @ W[idx[n]]
// N=262144, D_IN=D_OUT=256, NUM_TYPES=16, fp32 in/out.
// Strategy: bucket rows by type, pack W to bf16 MFMA-B layout, grouped GEMM
// with bf16 MFMA (fp32 accum). Memory-bound target ~516 MB HBM traffic.

#define NTYPES 16

typedef __bf16 bf16x8 __attribute__((ext_vector_type(8)));
typedef float f32x4 __attribute__((ext_vector_type(4)));

static __device__ __forceinline__ unsigned int f2bf_pk(float a, float b) {
  unsigned int ua = __float_as_uint(a);
  unsigned int ub = __float_as_uint(b);
  ua = (ua + 0x7FFFu + ((ua >> 16) & 1u)) >> 16;  // RNE f32->bf16
  ub = (ub + 0x7FFFu + ((ub >> 16) & 1u)) >> 16;
  return ua | (ub << 16);
}

// meta layout (unsigned int):
// [0..15]  cnt
// [16..31] off   (exclusive prefix of cnt)
// [32..47] cursor (scatter write positions, starts = off)
// [48..64] tileStart (prefix of ceil(cnt/64)), tileStart[16] = total tiles

__global__ void zero_meta_kernel(unsigned int* meta) {
  if (threadIdx.x < 128) meta[threadIdx.x] = 0;
}

__global__ void hist_kernel(const int* __restrict__ idx, int N,
                            unsigned int* __restrict__ meta) {
  __shared__ unsigned int h[NTYPES];
  if (threadIdx.x < NTYPES) h[threadIdx.x] = 0;
  __syncthreads();
  for (int n = blockIdx.x * 256 + threadIdx.x; n < N; n += gridDim.x * 256)
    atomicAdd(&h[idx[n] & 15], 1u);
  __syncthreads();
  if (threadIdx.x < NTYPES) atomicAdd(&meta[threadIdx.x], h[threadIdx.x]);
}

__global__ void prefix_kernel(unsigned int* meta) {
  if (threadIdx.x == 0) {
    unsigned int o = 0, ts = 0;
    for (int t = 0; t < NTYPES; t++) {
      meta[16 + t] = o;
      meta[32 + t] = o;
      meta[48 + t] = ts;
      o += meta[t];
      ts += (meta[t] + 63u) >> 6;
    }
    meta[64] = ts;
  }
}

__global__ void scatter_kernel(const int* __restrict__ idx, int N,
                               unsigned int* __restrict__ meta,
                               int* __restrict__ perm) {
  __shared__ unsigned int h[NTYPES];
  __shared__ unsigned int base[NTYPES];
  int b0 = blockIdx.x * 4096;
  if (threadIdx.x < NTYPES) h[threadIdx.x] = 0;
  __syncthreads();
  unsigned int lr[16];
  int tt[16];
#pragma unroll
  for (int i = 0; i < 16; i++) {
    int n = b0 + i * 256 + threadIdx.x;
    int t = (n < N) ? (idx[n] & 15) : 0;
    tt[i] = t;
    lr[i] = (n < N) ? atomicAdd(&h[t], 1u) : 0u;
  }
  __syncthreads();
  if (threadIdx.x < NTYPES)
    base[threadIdx.x] = atomicAdd(&meta[32 + threadIdx.x], h[threadIdx.x]);
  __syncthreads();
#pragma unroll
  for (int i = 0; i < 16; i++) {
    int n = b0 + i * 256 + threadIdx.x;
    if (n < N) perm[base[tt[i]] + lr[i]] = n;
  }
}

// Pack W[t][k][c] (fp32) -> Wp[(t*8+kblk)*256 + c][ks] (bf16), ks = k within
// 32-block. Lane fragment for mfma B-operand then reads 16 contiguous bytes.
__global__ void packW_kernel(const float* __restrict__ W,
                             unsigned short* __restrict__ Wp) {
  int id = blockIdx.x * 256 + threadIdx.x;  // (t*8+kblk)*256 + c, 32768 total
  int c = id & 255;
  int tk = id >> 8;  // t*8+kblk
  const float* src = W + (size_t)tk * 32 * 256 + c;
  unsigned int buf[16];
#pragma unroll
  for (int p = 0; p < 16; p++)
    buf[p] = f2bf_pk(src[(2 * p) * 256], src[(2 * p + 1) * 256]);
  uint4* d4 = (uint4*)(Wp + (size_t)id * 32);
#pragma unroll
  for (int p = 0; p < 4; p++)
    d4[p] = make_uint4(buf[4 * p], buf[4 * p + 1], buf[4 * p + 2], buf[4 * p + 3]);
}

// Grouped GEMM: one 64x256 output tile per block. 256 threads = 4 waves;
// wave w computes cols [w*64, w*64+64). x tile staged in LDS (bf16,
// XOR-swizzled rows to kill the stride-512B bank conflict); W fragments read
// from the packed bf16 buffer (L2-resident, coalesced 16B/lane).
__global__ __launch_bounds__(256) void gemm_kernel(
    const float* __restrict__ x, const unsigned short* __restrict__ Wp,
    const int* __restrict__ perm, const unsigned int* __restrict__ meta,
    float* __restrict__ out) {
  __shared__ uint4 ldsx[64 * 32];  // 64 rows x 256 k (bf16) = 32 KiB

  unsigned int b = blockIdx.x;
  unsigned int total = meta[64];
  if (b >= total) return;
  int t = 0;
  while (b >= meta[48 + t + 1]) t++;
  unsigned int off = meta[16 + t];
  unsigned int cnt = meta[t];
  unsigned int rowbase = off + (b - meta[48 + t]) * 64u;
  unsigned int rem = off + cnt - rowbase;
  int nrows = rem < 64u ? (int)rem : 64;

  int tid = threadIdx.x;
  {  // stage x tile: 4 threads per row, fp32 -> bf16, swizzled LDS
    int r = tid >> 2, q = tid & 3;
    if (r < nrows) {
      int pr = perm[rowbase + r];
      const float4* xr = (const float4*)(x + (size_t)pr * 256);
#pragma unroll
      for (int c0 = 0; c0 < 8; c0++) {
        int kchunk = q * 8 + c0;  // 8 bf16 per chunk
        float4 f0 = xr[kchunk * 2];
        float4 f1 = xr[kchunk * 2 + 1];
        uint4 v;
        v.x = f2bf_pk(f0.x, f0.y);
        v.y = f2bf_pk(f0.z, f0.w);
        v.z = f2bf_pk(f1.x, f1.y);
        v.w = f2bf_pk(f1.z, f1.w);
        ldsx[r * 32 + (kchunk ^ (r & 7))] = v;
      }
    } else {
      uint4 z = make_uint4(0u, 0u, 0u, 0u);
#pragma unroll
      for (int c0 = 0; c0 < 8; c0++)
        ldsx[r * 32 + ((q * 8 + c0) ^ (r & 7))] = z;
    }
  }
  __syncthreads();

  int l = tid & 63, w = tid >> 6;
  int lm = l & 15, lh = l >> 4;

  f32x4 acc[4][4];
#pragma unroll
  for (int i = 0; i < 4; i++)
#pragma unroll
    for (int j = 0; j < 4; j++) acc[i][j] = (f32x4){0.f, 0.f, 0.f, 0.f};

  const uint4* Wp4 = (const uint4*)Wp;
#pragma unroll
  for (int kk = 0; kk < 8; kk++) {
    bf16x8 a[4], bb[4];
#pragma unroll
    for (int fm = 0; fm < 4; fm++) {
      int r2 = fm * 16 + lm;
      a[fm] = __builtin_bit_cast(
          bf16x8, ldsx[r2 * 32 + ((kk * 4 + lh) ^ (r2 & 7))]);
    }
#pragma unroll
    for (int fn = 0; fn < 4; fn++) {
      int c = w * 64 + fn * 16 + lm;
      bb[fn] = __builtin_bit_cast(
          bf16x8, Wp4[(size_t)((t * 8 + kk) * 256 + c) * 4 + lh]);
    }
#pragma unroll
    for (int fm = 0; fm < 4; fm++)
#pragma unroll
      for (int fn = 0; fn < 4; fn++)
        acc[fm][fn] = __builtin_amdgcn_mfma_f32_16x16x32_bf16(
            a[fm], bb[fn], acc[fm][fn], 0, 0, 0);
  }

  // store: D layout col=lane&15, row=(lane>>4)*4+r_
#pragma unroll
  for (int fm = 0; fm < 4; fm++) {
#pragma unroll
    for (int r_ = 0; r_ < 4; r_++) {
      int rit = fm * 16 + lh * 4 + r_;
      if (rit < nrows) {
        int grow = perm[rowbase + rit];
        float* orow = out + (size_t)grow * 256 + w * 64 + lm;
#pragma unroll
        for (int fn = 0; fn < 4; fn++) orow[fn * 16] = acc[fm][fn][r_];
      }
    }
  }
}

extern "C" void kernel_launch(void* const* d_in, const int* in_sizes, int n_in,
                              void* d_out, int out_size, void* d_ws,
                              size_t ws_size, hipStream_t stream) {
  const float* x = (const float*)d_in[0];
  const int* idx = (const int*)d_in[1];
  const float* W = (const float*)d_in[2];
  float* out = (float*)d_out;
  int N = in_sizes[0] / 256;

  // ws layout: meta (512 B) | perm (N*4 B) | Wp (16*256*256*2 B)
  unsigned int* meta = (unsigned int*)d_ws;
  int* perm = (int*)((char*)d_ws + 512);
  unsigned short* Wp = (unsigned short*)((char*)d_ws + 512 + (size_t)N * 4);

  zero_meta_kernel<<<1, 128, 0, stream>>>(meta);
  hist_kernel<<<256, 256, 0, stream>>>(idx, N, meta);
  prefix_kernel<<<1, 64, 0, stream>>>(meta);
  packW_kernel<<<128, 256, 0, stream>>>(W, Wp);
  int nScatter = (N + 4095) / 4096;
  scatter_kernel<<<nScatter, 256, 0, stream>>>(idx, N, meta, perm);
  int maxTiles = N / 64 + NTYPES;
  gemm_kernel<<<maxTiles, 256, 0, stream>>>(x, Wp, perm, meta, out);
}

// Round 4
// 170.737 us; speedup vs baseline: 1.1215x; 1.1215x over previous
//
#include <hip/hip_runtime.h>
#include <hip/hip_bf16.h>

// IndexedLinear: out[n] = x[n] @ W[idx[n]]
// N=262144, D_IN=D_OUT=256, NUM_TYPES=16, fp32 in/out.
// Bucket rows by type -> grouped bf16-MFMA GEMM. Round 2 (resubmit #2 after
// repeated infra failures): tile descriptor table, W prefetch pipeline,
// 128-VGPR cap.

#define NTYPES 16

typedef __bf16 bf16x8 __attribute__((ext_vector_type(8)));
typedef float f32x4 __attribute__((ext_vector_type(4)));

static __device__ __forceinline__ unsigned int f2bf_pk(float a, float b) {
  unsigned int ua = __float_as_uint(a);
  unsigned int ub = __float_as_uint(b);
  ua = (ua + 0x7FFFu + ((ua >> 16) & 1u)) >> 16;  // RNE f32->bf16
  ub = (ub + 0x7FFFu + ((ub >> 16) & 1u)) >> 16;
  return ua | (ub << 16);
}

// meta layout (unsigned int):
// [0..15]  cnt
// [16..31] off   (exclusive prefix of cnt)
// [32..47] cursor (scatter write positions, starts = off)
// [48..64] tileStart (prefix of ceil(cnt/64)), tileStart[16] = total tiles

__global__ void zero_meta_kernel(unsigned int* meta) {
  if (threadIdx.x < 128) meta[threadIdx.x] = 0;
}

__global__ void hist_kernel(const int* __restrict__ idx, int N,
                            unsigned int* __restrict__ meta) {
  __shared__ unsigned int h[NTYPES];
  if (threadIdx.x < NTYPES) h[threadIdx.x] = 0;
  __syncthreads();
  for (int n = blockIdx.x * 256 + threadIdx.x; n < N; n += gridDim.x * 256)
    atomicAdd(&h[idx[n] & 15], 1u);
  __syncthreads();
  if (threadIdx.x < NTYPES) atomicAdd(&meta[threadIdx.x], h[threadIdx.x]);
}

__global__ void prefix_kernel(unsigned int* meta) {
  if (threadIdx.x == 0) {
    unsigned int o = 0, ts = 0;
    for (int t = 0; t < NTYPES; t++) {
      meta[16 + t] = o;
      meta[32 + t] = o;
      meta[48 + t] = ts;
      o += meta[t];
      ts += (meta[t] + 63u) >> 6;
    }
    meta[64] = ts;
  }
}

// One thread per tile: resolve (type, rowbase, nrows) once, so the GEMM
// kernel starts with a single uint2 load instead of a serial meta scan.
__global__ void tiles_kernel(const unsigned int* __restrict__ meta,
                             uint2* __restrict__ desc, int maxTiles) {
  __shared__ unsigned int ts[17], offs[16], cnts[16];
  if (threadIdx.x < 17) ts[threadIdx.x] = meta[48 + threadIdx.x];
  if (threadIdx.x < 16) {
    offs[threadIdx.x] = meta[16 + threadIdx.x];
    cnts[threadIdx.x] = meta[threadIdx.x];
  }
  __syncthreads();
  int tile = blockIdx.x * 256 + threadIdx.x;
  if (tile >= maxTiles) return;
  uint2 d = make_uint2(0u, 0u);
  if ((unsigned)tile < ts[16]) {
    int t = 0;
    while ((unsigned)tile >= ts[t + 1]) t++;
    unsigned int rowbase = offs[t] + ((unsigned)tile - ts[t]) * 64u;
    unsigned int rem = offs[t] + cnts[t] - rowbase;
    unsigned int nrows = rem < 64u ? rem : 64u;
    d = make_uint2(rowbase, (unsigned)t | (nrows << 8));
  }
  desc[tile] = d;
}

__global__ void scatter_kernel(const int* __restrict__ idx, int N,
                               unsigned int* __restrict__ meta,
                               int* __restrict__ perm) {
  __shared__ unsigned int h[NTYPES];
  __shared__ unsigned int base[NTYPES];
  int b0 = blockIdx.x * 4096;
  if (threadIdx.x < NTYPES) h[threadIdx.x] = 0;
  __syncthreads();
  unsigned int lr[16];
  int tt[16];
#pragma unroll
  for (int i = 0; i < 16; i++) {
    int n = b0 + i * 256 + threadIdx.x;
    int t = (n < N) ? (idx[n] & 15) : 0;
    tt[i] = t;
    lr[i] = (n < N) ? atomicAdd(&h[t], 1u) : 0u;
  }
  __syncthreads();
  if (threadIdx.x < NTYPES)
    base[threadIdx.x] = atomicAdd(&meta[32 + threadIdx.x], h[threadIdx.x]);
  __syncthreads();
#pragma unroll
  for (int i = 0; i < 16; i++) {
    int n = b0 + i * 256 + threadIdx.x;
    if (n < N) perm[base[tt[i]] + lr[i]] = n;
  }
}

// Pack W[t][k][c] (fp32) -> Wp[(t*8+kblk)*256 + c][ks] (bf16), ks = k within
// 32-block. Lane fragment for mfma B-operand then reads 16 contiguous bytes.
__global__ void packW_kernel(const float* __restrict__ W,
                             unsigned short* __restrict__ Wp) {
  int id = blockIdx.x * 256 + threadIdx.x;  // (t*8+kblk)*256 + c, 32768 total
  int c = id & 255;
  int tk = id >> 8;  // t*8+kblk
  const float* src = W + (size_t)tk * 32 * 256 + c;
  unsigned int buf[16];
#pragma unroll
  for (int p = 0; p < 16; p++)
    buf[p] = f2bf_pk(src[(2 * p) * 256], src[(2 * p + 1) * 256]);
  uint4* d4 = (uint4*)(Wp + (size_t)id * 32);
#pragma unroll
  for (int p = 0; p < 4; p++)
    d4[p] = make_uint4(buf[4 * p], buf[4 * p + 1], buf[4 * p + 2], buf[4 * p + 3]);
}

// Grouped GEMM: one 64x256 output tile per block. 256 threads = 4 waves;
// wave w computes cols [w*64, w*64+64). x tile staged in LDS (bf16, swizzled).
// W fragments stream from the packed bf16 buffer (L2-resident) with a
// one-step register prefetch across the K loop.
__global__ __launch_bounds__(256, 4) void gemm_kernel(
    const float* __restrict__ x, const unsigned short* __restrict__ Wp,
    const int* __restrict__ perm, const uint2* __restrict__ desc,
    float* __restrict__ out) {
  __shared__ uint4 ldsx[64 * 32];  // 64 rows x 256 k (bf16) = 32 KiB
  __shared__ int permS[64];

  uint2 dsc = desc[blockIdx.x];
  int nrows = (int)(dsc.y >> 8);
  if (nrows == 0) return;
  int t = (int)(dsc.y & 15u);
  unsigned int rowbase = dsc.x;

  int tid = threadIdx.x;
  int l = tid & 63, w = tid >> 6;
  int lm = l & 15, lh = l >> 4;

  const uint4* Wp4 = (const uint4*)Wp;
  // issue kk=0 W fragments early: overlaps the x gather below
  bf16x8 bbc[4], bbn[4];
#pragma unroll
  for (int fn = 0; fn < 4; fn++) {
    int c = w * 64 + fn * 16 + lm;
    bbc[fn] =
        __builtin_bit_cast(bf16x8, Wp4[(size_t)((t * 8) * 256 + c) * 4 + lh]);
  }

  {  // stage x tile: 4 threads per row, fp32 -> bf16, swizzled LDS
    int r = tid >> 2, q = tid & 3;
    if (r < nrows) {
      int pr = perm[rowbase + r];
      if (q == 0) permS[r] = pr;
      const float4* xr = (const float4*)(x + (size_t)pr * 256);
#pragma unroll
      for (int c0 = 0; c0 < 8; c0++) {
        int kchunk = q * 8 + c0;  // 8 bf16 per chunk
        float4 f0 = xr[kchunk * 2];
        float4 f1 = xr[kchunk * 2 + 1];
        uint4 v;
        v.x = f2bf_pk(f0.x, f0.y);
        v.y = f2bf_pk(f0.z, f0.w);
        v.z = f2bf_pk(f1.x, f1.y);
        v.w = f2bf_pk(f1.z, f1.w);
        ldsx[r * 32 + (kchunk ^ (r & 7))] = v;
      }
    } else {
      uint4 z = make_uint4(0u, 0u, 0u, 0u);
      if (q == 0) permS[r] = 0;
#pragma unroll
      for (int c0 = 0; c0 < 8; c0++)
        ldsx[r * 32 + ((q * 8 + c0) ^ (r & 7))] = z;
    }
  }
  __syncthreads();

  f32x4 acc[4][4];
#pragma unroll
  for (int i = 0; i < 4; i++)
#pragma unroll
    for (int j = 0; j < 4; j++) acc[i][j] = (f32x4){0.f, 0.f, 0.f, 0.f};

#pragma unroll
  for (int kk = 0; kk < 8; kk++) {
    bf16x8 a[4];
#pragma unroll
    for (int fm = 0; fm < 4; fm++) {
      int r2 = fm * 16 + lm;
      a[fm] = __builtin_bit_cast(bf16x8,
                                 ldsx[r2 * 32 + ((kk * 4 + lh) ^ (r2 & 7))]);
    }
    if (kk < 7) {
#pragma unroll
      for (int fn = 0; fn < 4; fn++) {
        int c = w * 64 + fn * 16 + lm;
        bbn[fn] = __builtin_bit_cast(
            bf16x8, Wp4[(size_t)((t * 8 + kk + 1) * 256 + c) * 4 + lh]);
      }
    }
#pragma unroll
    for (int fm = 0; fm < 4; fm++)
#pragma unroll
      for (int fn = 0; fn < 4; fn++)
        acc[fm][fn] = __builtin_amdgcn_mfma_f32_16x16x32_bf16(
            a[fm], bbc[fn], acc[fm][fn], 0, 0, 0);
    if (kk < 7) {
#pragma unroll
      for (int fn = 0; fn < 4; fn++) bbc[fn] = bbn[fn];
    }
  }

  // store: D layout col=lane&15, row=(lane>>4)*4+r_
#pragma unroll
  for (int fm = 0; fm < 4; fm++) {
#pragma unroll
    for (int r_ = 0; r_ < 4; r_++) {
      int rit = fm * 16 + lh * 4 + r_;
      if (rit < nrows) {
        int grow = permS[rit];
        float* orow = out + (size_t)grow * 256 + w * 64 + lm;
#pragma unroll
        for (int fn = 0; fn < 4; fn++) orow[fn * 16] = acc[fm][fn][r_];
      }
    }
  }
}

extern "C" void kernel_launch(void* const* d_in, const int* in_sizes, int n_in,
                              void* d_out, int out_size, void* d_ws,
                              size_t ws_size, hipStream_t stream) {
  const float* x = (const float*)d_in[0];
  const int* idx = (const int*)d_in[1];
  const float* W = (const float*)d_in[2];
  float* out = (float*)d_out;
  int N = in_sizes[0] / 256;
  int maxTiles = N / 64 + NTYPES;

  // ws layout: meta (512 B) | desc (maxTiles*8 B) | perm (N*4 B) | Wp (2 MiB)
  unsigned int* meta = (unsigned int*)d_ws;
  uint2* desc = (uint2*)((char*)d_ws + 512);
  int* perm = (int*)((char*)d_ws + 512 + (size_t)maxTiles * 8);
  unsigned short* Wp =
      (unsigned short*)((char*)d_ws + 512 + (size_t)maxTiles * 8 +
                        (size_t)N * 4);

  zero_meta_kernel<<<1, 128, 0, stream>>>(meta);
  hist_kernel<<<256, 256, 0, stream>>>(idx, N, meta);
  prefix_kernel<<<1, 64, 0, stream>>>(meta);
  packW_kernel<<<128, 256, 0, stream>>>(W, Wp);
  tiles_kernel<<<(maxTiles + 255) / 256, 256, 0, stream>>>(meta, desc,
                                                           maxTiles);
  int nScatter = (N + 4095) / 4096;
  scatter_kernel<<<nScatter, 256, 0, stream>>>(idx, N, meta, perm);
  gemm_kernel<<<maxTiles, 256, 0, stream>>>(x, Wp, perm, desc, out);
}